// Round 16
// baseline (68.234 us; speedup 1.0000x reference)
//
#include <hip/hip_runtime.h>

typedef float f32x16 __attribute__((ext_vector_type(16)));
typedef short bf16x8 __attribute__((ext_vector_type(8)));

constexpr int SROWS  = 128;   // stationary rec rows per block (4 A-frags)
constexpr int NSLICE = 2;     // streaming col-slices -> grid 512 = 2 blocks/CU

__device__ inline short f2bf(float x) {               // RNE float->bf16 bits
    unsigned u = __float_as_uint(x);
    unsigned r = (u + 0x7fffu + ((u >> 16) & 1u)) >> 16;
    return (short)r;
}
__device__ inline float bf2f(short h) {
    return __uint_as_float(((unsigned)(unsigned short)h) << 16);
}
// min of 16 via min3-friendly tree (8 instrs)
__device__ inline float vmin16_t(f32x16 v) {
    float t1 = fminf(fminf(v[0], v[1]), v[2]);
    float t2 = fminf(fminf(v[3], v[4]), v[5]);
    float t3 = fminf(fminf(v[6], v[7]), v[8]);
    float t4 = fminf(fminf(v[9], v[10]), v[11]);
    float t5 = fminf(fminf(v[12], v[13]), v[14]);
    float u1 = fminf(fminf(t1, t2), t3);
    float u2 = fminf(fminf(t4, t5), v[15]);
    return fminf(u1, u2);
}

// K-slot map (k = 8*half + j), d = qw + pw - 2(qh+ql).(ph+pl) [ql.pl dropped]:
// A(query role, rec) h0={-2qh(3), -2ql(3), qwh, qwl}  h1={-2qh(3), 1, 1, 0,0,0}
// B(point role, data) h0={ph(3), ph(3), 1, 1}         h1={pl(3), pwh, pwl, 0,0,0}
// Shared (half,j) slot space -> mapping-agnostic (r11-r15: absmax 0.0).
__global__ __launch_bounds__(256)
void chamfer_prep(const float* __restrict__ rec, const float* __restrict__ data,
                  bf16x8* __restrict__ Ar, bf16x8* __restrict__ Bd,
                  int N, int M, int B)
{
    const int i = blockIdx.x * 256 + threadIdx.x;
    const int tot0 = B * N, tot = tot0 + B * M;
    if (i >= tot) return;
    const short ONE = 0x3F80;
    const bool isRec = i < tot0;
    const int j = isRec ? i : i - tot0;
    const float* p = (isRec ? rec : data) + (size_t)j * 3;
    const float x = p[0], y = p[1], z = p[2];
    const float w = fmaf(x, x, fmaf(y, y, z * z));
    const short hx = f2bf(x), hy = f2bf(y), hz = f2bf(z);
    const float fx = bf2f(hx), fy = bf2f(hy), fz = bf2f(hz);
    const short wh = f2bf(w);
    const short wl = f2bf(w - bf2f(wh));
    if (isRec) {
        const short nhx = f2bf(-2.f * fx), nhy = f2bf(-2.f * fy), nhz = f2bf(-2.f * fz);
        const short nlx = f2bf(-2.f * (x - fx));
        const short nly = f2bf(-2.f * (y - fy));
        const short nlz = f2bf(-2.f * (z - fz));
        bf16x8 A0 = {nhx, nhy, nhz, nlx, nly, nlz, wh, wl};
        bf16x8 A1 = {nhx, nhy, nhz, ONE, ONE, 0, 0, 0};
        Ar[2 * (size_t)j] = A0; Ar[2 * (size_t)j + 1] = A1;
    } else {
        const short lx = f2bf(x - fx), ly = f2bf(y - fy), lz = f2bf(z - fz);
        bf16x8 B0 = {hx, hy, hz, hx, hy, hz, ONE, ONE};
        bf16x8 B1 = {lx, ly, lz, wh, wl, 0, 0, 0};
        Bd[2 * (size_t)j] = B0; Bd[2 * (size_t)j + 1] = B1;
    }
}

// Fused single pass: each distance computed ONCE. Stationary rec rows (rmin
// accumulates in registers; expensive butterfly reduce happens once per
// block); streaming data cols (cheap in-lane tree + xor32 + store per iter).
// 262144 MFMAs total — half of the two-pass structure. launch_bounds(256,2):
// 256-reg budget (no spill/AGPR pressure); grid 512 = 2 blocks/CU.
__global__ __launch_bounds__(256, 2)
void chamfer_fused_kernel(const bf16x8* __restrict__ Ar,
                          const bf16x8* __restrict__ Bd,
                          float* __restrict__ colpart,   // [B][N/128][M]
                          float* __restrict__ rowpart,   // [B][8][N]
                          int N, int M, int B)
{
    const int nSB = N / SROWS;
    int idx = blockIdx.x;
    const int sl = idx % NSLICE; idx /= NSLICE;
    const int sb = idx % nSB;
    const int b  = idx / nSB;

    const int lane = threadIdx.x & 63, wave = threadIdx.x >> 6;
    const int c = lane & 31, h = lane >> 5;

    const bf16x8* __restrict__ Ab = Ar + 2 * ((size_t)b * N + sb * SROWS);
    const bf16x8* __restrict__ Bb = Bd + 2 * ((size_t)b * M);
    float* __restrict__ colBase = colpart + ((size_t)b * nSB + sb) * M;

    bf16x8 a0 = Ab[2 * (0 * 32 + c) + h];
    bf16x8 a1 = Ab[2 * (1 * 32 + c) + h];
    bf16x8 a2 = Ab[2 * (2 * 32 + c) + h];
    bf16x8 a3 = Ab[2 * (3 * 32 + c) + h];

    f32x16 zacc, rmin0, rmin1, rmin2, rmin3;
    #pragma unroll
    for (int r = 0; r < 16; ++r) {
        zacc[r] = 0.f;
        rmin0[r] = 3.4e38f; rmin1[r] = 3.4e38f;
        rmin2[r] = 3.4e38f; rmin3[r] = 3.4e38f;
    }

    const int TS32   = M >> 5;
    const int TSlice = TS32 / NSLICE;            // 128 col-tiles per slice
    const int t0     = sl * TSlice + wave;
    const int tEnd   = (sl + 1) * TSlice;

    bf16x8 bcur = Bb[2 * ((size_t)t0 * 32 + c) + h];
    bf16x8 bn1  = Bb[2 * ((size_t)(t0 + 4) * 32 + c) + h];

    for (int t = t0; t < tEnd; t += 4) {
        int tn = t + 8; if (tn >= tEnd) tn = t0;            // harmless reload
        bf16x8 bn2 = Bb[2 * ((size_t)tn * 32 + c) + h];     // 2-ahead prefetch

        f32x16 d0 = __builtin_amdgcn_mfma_f32_32x32x16_bf16(a0, bcur, zacc, 0, 0, 0);
        #pragma unroll
        for (int r = 0; r < 16; ++r) rmin0[r] = fminf(rmin0[r], d0[r]);
        float cm = vmin16_t(d0);
        f32x16 d1 = __builtin_amdgcn_mfma_f32_32x32x16_bf16(a1, bcur, zacc, 0, 0, 0);
        #pragma unroll
        for (int r = 0; r < 16; ++r) rmin1[r] = fminf(rmin1[r], d1[r]);
        cm = fminf(cm, vmin16_t(d1));
        f32x16 d2 = __builtin_amdgcn_mfma_f32_32x32x16_bf16(a2, bcur, zacc, 0, 0, 0);
        #pragma unroll
        for (int r = 0; r < 16; ++r) rmin2[r] = fminf(rmin2[r], d2[r]);
        cm = fminf(cm, vmin16_t(d2));
        f32x16 d3 = __builtin_amdgcn_mfma_f32_32x32x16_bf16(a3, bcur, zacc, 0, 0, 0);
        #pragma unroll
        for (int r = 0; r < 16; ++r) rmin3[r] = fminf(rmin3[r], d3[r]);
        cm = fminf(cm, vmin16_t(d3));

        cm = fminf(cm, __shfl_xor(cm, 32));                 // merge h-halves: 128 rows
        if (lane < 32)
            colBase[(size_t)t * 32 + c] = cm;               // 128B coalesced store

        bcur = bn1; bn1 = bn2;
    }

    // Once-per-block tail: butterfly row-mins over the 32 c-lanes; each
    // (slice, wave) writes its own rowpart layer -> no cross-wave merge.
    float* __restrict__ rp =
        rowpart + ((size_t)b * (NSLICE * 4) + (sl * 4 + wave)) * N + sb * SROWS;
#define ROWRED(RM, F)                                                      \
    _Pragma("unroll")                                                      \
    for (int r = 0; r < 16; ++r) {                                         \
        float v = RM[r];                                                   \
        v = fminf(v, __shfl_xor(v, 1));                                    \
        v = fminf(v, __shfl_xor(v, 2));                                    \
        v = fminf(v, __shfl_xor(v, 4));                                    \
        v = fminf(v, __shfl_xor(v, 8));                                    \
        v = fminf(v, __shfl_xor(v, 16));                                   \
        if (c == 0)                                                        \
            rp[(F) * 32 + (r & 3) + 8 * (r >> 2) + 4 * h] = v;             \
    }
    ROWRED(rmin0, 0) ROWRED(rmin1, 1) ROWRED(rmin2, 2) ROWRED(rmin3, 3)
#undef ROWRED
}

// Stage 2: cols: min over N/128 block-partials; rows: min over 8 layers.
__global__ __launch_bounds__(256)
void chamfer_stage2(const float* __restrict__ colpart,
                    const float* __restrict__ rowpart,
                    float* __restrict__ bsums, int N, int M, int B)
{
    __shared__ float wsum[4];
    const int gid = blockIdx.x * 256 + threadIdx.x;
    const int nD = B * M;
    const int nSB = N / SROWS;

    const float* base; size_t stride; int depth;
    if (gid < nD) {
        const int b = gid / M, col = gid - b * M;
        base = colpart + ((size_t)b * nSB) * M + col;
        stride = M; depth = nSB;
    } else {
        const int g = gid - nD;
        const int b = g / N, row = g - b * N;
        base = rowpart + ((size_t)b * (NSLICE * 4)) * N + row;
        stride = N; depth = NSLICE * 4;
    }
    float m0 = 3.4e38f, m1 = 3.4e38f, m2 = 3.4e38f, m3 = 3.4e38f;
    int s = 0;
    for (; s + 4 <= depth; s += 4) {
        m0 = fminf(m0, base[(s + 0) * stride]);
        m1 = fminf(m1, base[(s + 1) * stride]);
        m2 = fminf(m2, base[(s + 2) * stride]);
        m3 = fminf(m3, base[(s + 3) * stride]);
    }
    for (; s < depth; ++s) m0 = fminf(m0, base[s * stride]);
    float d = fmaxf(fminf(fminf(m0, m1), fminf(m2, m3)), 0.f);

    for (int off = 32; off; off >>= 1) d += __shfl_down(d, off);
    if ((threadIdx.x & 63) == 0) wsum[threadIdx.x >> 6] = d;
    __syncthreads();
    if (threadIdx.x == 0)
        bsums[blockIdx.x] = wsum[0] + wsum[1] + wsum[2] + wsum[3];
}

// Finalize: mean_b( max(recsum_b/N, datasum_b/M) )
__global__ __launch_bounds__(256)
void chamfer_finalize(const float* __restrict__ bsums, float* __restrict__ out,
                      int N, int M, int B)
{
    __shared__ float smem[512];
    __shared__ float seg[16];
    const int ncD = M >> 8, ncR = N >> 8;       // stage2 blocks per batch
    const int nD  = B * ncD, ntot = nD + B * ncR;
    const int tid = threadIdx.x;
    for (int i = tid; i < ntot; i += 256) smem[i] = bsums[i];
    __syncthreads();
    if (tid < 2 * B) {
        const int dir = tid / B, bb = tid % B;   // dir0 = data(cols), dir1 = rec(rows)
        float s = 0.f;
        if (dir == 0) for (int i = 0; i < ncD; ++i) s += smem[bb * ncD + i];
        else          for (int i = 0; i < ncR; ++i) s += smem[nD + bb * ncR + i];
        seg[tid] = s;
    }
    __syncthreads();
    if (tid == 0) {
        float acc = 0.f;
        for (int bb = 0; bb < B; ++bb)
            acc += fmaxf(seg[B + bb] / (float)N, seg[bb] / (float)M);
        out[0] = acc / (float)B;
    }
}

extern "C" void kernel_launch(void* const* d_in, const int* in_sizes, int n_in,
                              void* d_out, int out_size, void* d_ws, size_t ws_size,
                              hipStream_t stream)
{
    const float* rec  = (const float*)d_in[0];
    const float* data = (const float*)d_in[1];
    const int B = 4;
    const int N = in_sizes[0] / (B * 3);
    const int M = in_sizes[1] / (B * 3);
    const int tot = B * (N + M);
    const int nSB = N / SROWS;

    // ws: Ar 1MB | Bd 1MB | colpart 8.4MB | rowpart 1MB | bsums
    char* w = (char*)d_ws;
    bf16x8* Ar = (bf16x8*)w;  w += (size_t)B * N * 2 * sizeof(bf16x8);
    bf16x8* Bd = (bf16x8*)w;  w += (size_t)B * M * 2 * sizeof(bf16x8);
    float* colpart = (float*)w;  w += (size_t)B * nSB * M * sizeof(float);
    float* rowpart = (float*)w;  w += (size_t)B * (NSLICE * 4) * N * sizeof(float);
    float* bsums = (float*)w;

    chamfer_prep<<<(tot + 255) / 256, 256, 0, stream>>>(rec, data, Ar, Bd, N, M, B);
    const int G = B * nSB * NSLICE;                       // 512 blocks
    chamfer_fused_kernel<<<G, 256, 0, stream>>>(Ar, Bd, colpart, rowpart, N, M, B);
    chamfer_stage2<<<tot / 256, 256, 0, stream>>>(colpart, rowpart, bsums, N, M, B);
    chamfer_finalize<<<1, 256, 0, stream>>>(bsums, (float*)d_out, N, M, B);
}

// Round 19
// 44.293 us; speedup vs baseline: 1.5405x; 1.5405x over previous
//
#include <hip/hip_runtime.h>

typedef float f32x16 __attribute__((ext_vector_type(16)));
typedef short bf16x8 __attribute__((ext_vector_type(8)));

constexpr int SROWS  = 256;   // stationary rows per block (8 frags)
constexpr int NSLICE = 4;     // streaming slices per pass -> grid 1024

// Inline-asm MFMA, early-clobber D (r17 lesson: "=v" alone lets D alias inputs).
#define MFMA_ASM(D, A, Bv, C)                                              \
    asm("v_mfma_f32_32x32x16_bf16 %0, %1, %2, %3"                          \
        : "=&v"(D) : "v"(A), "v"(Bv), "v"(C))

// Hazard cover (r18 lesson): raw-asm MFMA is invisible to the compiler's
// hazard recognizer; a 16-pass MFMA dst needs ~18 cycles before a VALU read.
// 3x s_nop 7 = 24 cycles; "+v" ties order this between the MFMAs and their
// consumers (mins read the pin's outputs). Per-wave stall only — TLP hides it.
#define MFMA_WAIT2(D0, D1)                                                 \
    asm volatile("s_nop 7\n\ts_nop 7\n\ts_nop 7" : "+v"(D0), "+v"(D1))

__device__ inline short f2bf(float x) {               // RNE float->bf16 bits
    unsigned u = __float_as_uint(x);
    unsigned r = (u + 0x7fffu + ((u >> 16) & 1u)) >> 16;
    return (short)r;
}
__device__ inline float bf2f(short h) {
    return __uint_as_float(((unsigned)(unsigned short)h) << 16);
}
// min of 16 via min3-friendly tree (8 instrs)
__device__ inline float vmin16_t(f32x16 v) {
    float t1 = fminf(fminf(v[0], v[1]), v[2]);
    float t2 = fminf(fminf(v[3], v[4]), v[5]);
    float t3 = fminf(fminf(v[6], v[7]), v[8]);
    float t4 = fminf(fminf(v[9], v[10]), v[11]);
    float t5 = fminf(fminf(v[12], v[13]), v[14]);
    float u1 = fminf(fminf(t1, t2), t3);
    float u2 = fminf(fminf(t4, t5), v[15]);
    return fminf(u1, u2);
}

// K-slot map (k = 8*half + j), d = qw + pw - 2(qh+ql).(ph+pl) [ql.pl dropped]:
// A(query role) h0={-2qh(3), -2ql(3), qwh, qwl}  h1={-2qh(3), 1, 1, 0,0,0}
// B(point role) h0={ph(3), ph(3), 1, 1}          h1={pl(3), pwh, pwl, 0,0,0}
// Shared (half,j) slot space -> mapping-agnostic (r11-r16: absmax 0.0).
__global__ __launch_bounds__(256)
void chamfer_prep(const float* __restrict__ rec, const float* __restrict__ data,
                  bf16x8* __restrict__ Ar, bf16x8* __restrict__ Br,
                  bf16x8* __restrict__ Ad, bf16x8* __restrict__ Bd,
                  int N, int M, int B)
{
    const int i = blockIdx.x * 256 + threadIdx.x;
    const int tot0 = B * N, tot = tot0 + B * M;
    if (i >= tot) return;
    const short ONE = 0x3F80;
    const bool isRec = i < tot0;
    const int j = isRec ? i : i - tot0;
    const float* p = (isRec ? rec : data) + (size_t)j * 3;
    const float x = p[0], y = p[1], z = p[2];
    const float w = fmaf(x, x, fmaf(y, y, z * z));
    const short hx = f2bf(x), hy = f2bf(y), hz = f2bf(z);
    const float fx = bf2f(hx), fy = bf2f(hy), fz = bf2f(hz);
    const short nhx = f2bf(-2.f * fx), nhy = f2bf(-2.f * fy), nhz = f2bf(-2.f * fz);
    const short nlx = f2bf(-2.f * (x - fx));
    const short nly = f2bf(-2.f * (y - fy));
    const short nlz = f2bf(-2.f * (z - fz));
    const short lx = f2bf(x - fx), ly = f2bf(y - fy), lz = f2bf(z - fz);
    const short wh = f2bf(w);
    const short wl = f2bf(w - bf2f(wh));

    bf16x8 A0 = {nhx, nhy, nhz, nlx, nly, nlz, wh, wl};
    bf16x8 A1 = {nhx, nhy, nhz, ONE, ONE, 0, 0, 0};
    bf16x8 B0 = {hx, hy, hz, hx, hy, hz, ONE, ONE};
    bf16x8 B1 = {lx, ly, lz, wh, wl, 0, 0, 0};

    bf16x8* Adst = (isRec ? Ar : Ad) + 2 * (size_t)j;
    bf16x8* Bdst = (isRec ? Br : Bd) + 2 * (size_t)j;
    Adst[0] = A0; Adst[1] = A1;
    Bdst[0] = B0; Bdst[1] = B1;
}

// Stage 1: two symmetric passes (32x32x16 MFMA via inline asm, arch-VGPR D,
// explicit hazard nops). 8 MFMAs per B-load + 2-deep rotating prefetch.
__global__ __launch_bounds__(256, 4)
void chamfer_mfma_kernel(const bf16x8* __restrict__ Ar, const bf16x8* __restrict__ Bd,
                         const bf16x8* __restrict__ Ad, const bf16x8* __restrict__ Br,
                         float* __restrict__ part_data,   // [B][N/256][M]
                         float* __restrict__ part_rec,    // [B][M/256][N]
                         int N, int M, int B)
{
    const int nSB1 = N / SROWS;
    const int G1   = B * nSB1 * NSLICE;

    const bf16x8* Ap; const bf16x8* Bp; float* outp;
    int S, T, idx;
    if ((int)blockIdx.x < G1) {
        Ap = Ar; Bp = Bd; outp = part_data; S = N; T = M; idx = blockIdx.x;
    } else {
        Ap = Ad; Bp = Br; outp = part_rec;  S = M; T = N; idx = blockIdx.x - G1;
    }
    const int nSB = S / SROWS;
    const int sl  = idx % NSLICE; idx /= NSLICE;
    const int sb  = idx % nSB;
    const int b   = idx / nSB;

    const int lane = threadIdx.x & 63, wave = threadIdx.x >> 6;
    const int c = lane & 31, h = lane >> 5;

    const bf16x8* __restrict__ Ab = Ap + 2 * ((size_t)b * S + sb * SROWS);
    const bf16x8* __restrict__ Bb = Bp + 2 * ((size_t)b * T);
    float* __restrict__ outBase = outp + ((size_t)b * nSB + sb) * T;

    bf16x8 a0 = Ab[2 * (0 * 32 + c) + h];
    bf16x8 a1 = Ab[2 * (1 * 32 + c) + h];
    bf16x8 a2 = Ab[2 * (2 * 32 + c) + h];
    bf16x8 a3 = Ab[2 * (3 * 32 + c) + h];
    bf16x8 a4 = Ab[2 * (4 * 32 + c) + h];
    bf16x8 a5 = Ab[2 * (5 * 32 + c) + h];
    bf16x8 a6 = Ab[2 * (6 * 32 + c) + h];
    bf16x8 a7 = Ab[2 * (7 * 32 + c) + h];

    f32x16 zacc;
    #pragma unroll
    for (int r = 0; r < 16; ++r) zacc[r] = 0.f;

    const int TS32   = T >> 5;
    const int TSlice = TS32 / NSLICE;            // 64 col-tiles per slice
    const int t0     = sl * TSlice + wave;
    const int tEnd   = (sl + 1) * TSlice;

    // 2-deep rotating prefetch: loads for t+4 and t+8 in flight while
    // computing t.
    bf16x8 bcur = Bb[2 * ((size_t)t0 * 32 + c) + h];
    bf16x8 bn1  = Bb[2 * ((size_t)(t0 + 4) * 32 + c) + h];

    for (int t = t0; t < tEnd; t += 4) {
        int tn = t + 8; if (tn >= tEnd) tn = t0;            // harmless reload
        bf16x8 bn2 = Bb[2 * ((size_t)tn * 32 + c) + h];     // 2-ahead

        f32x16 d0, d1, acc;
        MFMA_ASM(d0, a0, bcur, zacc);
        MFMA_ASM(d1, a1, bcur, zacc);
        MFMA_WAIT2(d0, d1);
        #pragma unroll
        for (int r = 0; r < 16; ++r) acc[r] = fminf(d0[r], d1[r]);
        MFMA_ASM(d0, a2, bcur, zacc);
        MFMA_ASM(d1, a3, bcur, zacc);
        MFMA_WAIT2(d0, d1);
        #pragma unroll
        for (int r = 0; r < 16; ++r) acc[r] = fminf(fminf(d0[r], d1[r]), acc[r]);
        MFMA_ASM(d0, a4, bcur, zacc);
        MFMA_ASM(d1, a5, bcur, zacc);
        MFMA_WAIT2(d0, d1);
        #pragma unroll
        for (int r = 0; r < 16; ++r) acc[r] = fminf(fminf(d0[r], d1[r]), acc[r]);
        MFMA_ASM(d0, a6, bcur, zacc);
        MFMA_ASM(d1, a7, bcur, zacc);
        MFMA_WAIT2(d0, d1);
        #pragma unroll
        for (int r = 0; r < 16; ++r) acc[r] = fminf(fminf(d0[r], d1[r]), acc[r]);

        float cm = vmin16_t(acc);                           // lane's 16 rows
        cm = fminf(cm, __shfl_xor(cm, 32));                 // merge halves: 256 rows
        if (lane < 32)
            outBase[(size_t)t * 32 + c] = cm;               // 128B coalesced store

        bcur = bn1; bn1 = bn2;
    }
}

// Stage 2: per point, min over the nSB stationary-block partials, clamp, sum.
__global__ __launch_bounds__(256)
void chamfer_stage2(const float* __restrict__ part_data,
                    const float* __restrict__ part_rec,
                    float* __restrict__ bsums, int N, int M, int B)
{
    __shared__ float wsum[4];
    const int gid = blockIdx.x * 256 + threadIdx.x;
    const int nD = B * M;

    const float* base; size_t stride; int depth;
    if (gid < nD) {
        const int b = gid / M, col = gid - b * M;
        base = part_data + ((size_t)b * (N / SROWS)) * M + col;
        stride = M; depth = N / SROWS;
    } else {
        const int g = gid - nD;
        const int b = g / N, col = g - b * N;
        base = part_rec + ((size_t)b * (M / SROWS)) * N + col;
        stride = N; depth = M / SROWS;
    }
    float m0 = 3.4e38f, m1 = 3.4e38f, m2 = 3.4e38f, m3 = 3.4e38f;
    int s = 0;
    for (; s + 4 <= depth; s += 4) {
        m0 = fminf(m0, base[(s + 0) * stride]);
        m1 = fminf(m1, base[(s + 1) * stride]);
        m2 = fminf(m2, base[(s + 2) * stride]);
        m3 = fminf(m3, base[(s + 3) * stride]);
    }
    for (; s < depth; ++s) m0 = fminf(m0, base[s * stride]);
    float d = fmaxf(fminf(fminf(m0, m1), fminf(m2, m3)), 0.f);

    for (int off = 32; off; off >>= 1) d += __shfl_down(d, off);
    if ((threadIdx.x & 63) == 0) wsum[threadIdx.x >> 6] = d;
    __syncthreads();
    if (threadIdx.x == 0)
        bsums[blockIdx.x] = wsum[0] + wsum[1] + wsum[2] + wsum[3];
}

// Finalize: mean_b( max(recsum_b/N, datasum_b/M) )
__global__ __launch_bounds__(256)
void chamfer_finalize(const float* __restrict__ bsums, float* __restrict__ out,
                      int N, int M, int B)
{
    __shared__ float smem[512];
    __shared__ float seg[16];
    const int ncD = M >> 8, ncR = N >> 8;       // stage2 blocks per batch
    const int nD  = B * ncD, ntot = nD + B * ncR;
    const int tid = threadIdx.x;
    for (int i = tid; i < ntot; i += 256) smem[i] = bsums[i];
    __syncthreads();
    if (tid < 2 * B) {
        const int dir = tid / B, bb = tid % B;   // dir0 = data, dir1 = rec
        float s = 0.f;
        if (dir == 0) for (int i = 0; i < ncD; ++i) s += smem[bb * ncD + i];
        else          for (int i = 0; i < ncR; ++i) s += smem[nD + bb * ncR + i];
        seg[tid] = s;
    }
    __syncthreads();
    if (tid == 0) {
        float acc = 0.f;
        for (int bb = 0; bb < B; ++bb)
            acc += fmaxf(seg[B + bb] / (float)N, seg[bb] / (float)M);
        out[0] = acc / (float)B;
    }
}

extern "C" void kernel_launch(void* const* d_in, const int* in_sizes, int n_in,
                              void* d_out, int out_size, void* d_ws, size_t ws_size,
                              hipStream_t stream)
{
    const float* rec  = (const float*)d_in[0];
    const float* data = (const float*)d_in[1];
    const int B = 4;
    const int N = in_sizes[0] / (B * 3);
    const int M = in_sizes[1] / (B * 3);
    const int tot = B * (N + M);

    // ws: Ar 1MB | Br 1MB | Ad 1MB | Bd 1MB | part_data 4.2MB | part_rec 4.2MB
    char* w = (char*)d_ws;
    bf16x8* Ar = (bf16x8*)w;  w += (size_t)B * N * 2 * sizeof(bf16x8);
    bf16x8* Br = (bf16x8*)w;  w += (size_t)B * N * 2 * sizeof(bf16x8);
    bf16x8* Ad = (bf16x8*)w;  w += (size_t)B * M * 2 * sizeof(bf16x8);
    bf16x8* Bd = (bf16x8*)w;  w += (size_t)B * M * 2 * sizeof(bf16x8);
    float* part_data = (float*)w;  w += (size_t)B * (N / SROWS) * M * sizeof(float);
    float* part_rec  = (float*)w;  w += (size_t)B * (M / SROWS) * N * sizeof(float);
    float* bsums = (float*)w;

    chamfer_prep<<<(tot + 255) / 256, 256, 0, stream>>>(rec, data, Ar, Br, Ad, Bd,
                                                        N, M, B);
    const int G = B * (N / SROWS) * NSLICE + B * (M / SROWS) * NSLICE;  // 1024
    chamfer_mfma_kernel<<<G, 256, 0, stream>>>(Ar, Bd, Ad, Br,
                                               part_data, part_rec, N, M, B);
    chamfer_stage2<<<tot / 256, 256, 0, stream>>>(part_data, part_rec, bsums,
                                                  N, M, B);
    chamfer_finalize<<<1, 256, 0, stream>>>(bsums, (float*)d_out, N, M, B);
}

// Round 20
// 41.303 us; speedup vs baseline: 1.6521x; 1.0724x over previous
//
#include <hip/hip_runtime.h>

typedef float f32x16 __attribute__((ext_vector_type(16)));
typedef short bf16x8 __attribute__((ext_vector_type(8)));

constexpr int SROWS  = 256;   // stationary rows per block (8 frags) - proven best
constexpr int NSLICE = 4;     // streaming slices per pass -> grid 1024

__device__ inline short f2bf(float x) {               // RNE float->bf16 bits
    unsigned u = __float_as_uint(x);
    unsigned r = (u + 0x7fffu + ((u >> 16) & 1u)) >> 16;
    return (short)r;
}
__device__ inline float bf2f(short h) {
    return __uint_as_float(((unsigned)(unsigned short)h) << 16);
}
// min of 16 via min3-friendly tree (8 instrs)
__device__ inline float vmin16_t(f32x16 v) {
    float t1 = fminf(fminf(v[0], v[1]), v[2]);
    float t2 = fminf(fminf(v[3], v[4]), v[5]);
    float t3 = fminf(fminf(v[6], v[7]), v[8]);
    float t4 = fminf(fminf(v[9], v[10]), v[11]);
    float t5 = fminf(fminf(v[12], v[13]), v[14]);
    float u1 = fminf(fminf(t1, t2), t3);
    float u2 = fminf(fminf(t4, t5), v[15]);
    return fminf(u1, u2);
}

// K-slot map (k = 8*half + j), d = qw + pw - 2(qh+ql).(ph+pl) [ql.pl dropped]:
// A(query role) h0={-2qh(3), -2ql(3), qwh, qwl}  h1={-2qh(3), 1, 1, 0,0,0}
// B(point role) h0={ph(3), ph(3), 1, 1}          h1={pl(3), pwh, pwl, 0,0,0}
// Shared (half,j) slot space -> mapping-agnostic (r11-r16,r19: absmax 0.0).
__global__ __launch_bounds__(256)
void chamfer_prep(const float* __restrict__ rec, const float* __restrict__ data,
                  bf16x8* __restrict__ Ar, bf16x8* __restrict__ Br,
                  bf16x8* __restrict__ Ad, bf16x8* __restrict__ Bd,
                  int N, int M, int B)
{
    const int i = blockIdx.x * 256 + threadIdx.x;
    const int tot0 = B * N, tot = tot0 + B * M;
    if (i >= tot) return;
    const short ONE = 0x3F80;
    const bool isRec = i < tot0;
    const int j = isRec ? i : i - tot0;
    const float* p = (isRec ? rec : data) + (size_t)j * 3;
    const float x = p[0], y = p[1], z = p[2];
    const float w = fmaf(x, x, fmaf(y, y, z * z));
    const short hx = f2bf(x), hy = f2bf(y), hz = f2bf(z);
    const float fx = bf2f(hx), fy = bf2f(hy), fz = bf2f(hz);
    const short nhx = f2bf(-2.f * fx), nhy = f2bf(-2.f * fy), nhz = f2bf(-2.f * fz);
    const short nlx = f2bf(-2.f * (x - fx));
    const short nly = f2bf(-2.f * (y - fy));
    const short nlz = f2bf(-2.f * (z - fz));
    const short lx = f2bf(x - fx), ly = f2bf(y - fy), lz = f2bf(z - fz);
    const short wh = f2bf(w);
    const short wl = f2bf(w - bf2f(wh));

    bf16x8 A0 = {nhx, nhy, nhz, nlx, nly, nlz, wh, wl};
    bf16x8 A1 = {nhx, nhy, nhz, ONE, ONE, 0, 0, 0};
    bf16x8 B0 = {hx, hy, hz, hx, hy, hz, ONE, ONE};
    bf16x8 B1 = {lx, ly, lz, wh, wl, 0, 0, 0};

    bf16x8* Adst = (isRec ? Ar : Ad) + 2 * (size_t)j;
    bf16x8* Bdst = (isRec ? Br : Bd) + 2 * (size_t)j;
    Adst[0] = A0; Adst[1] = A1;
    Bdst[0] = B0; Bdst[1] = B1;
}

// Stage 1: two symmetric passes (32x32x16 MFMA intrinsics). 8 MFMAs per
// B-load + 2-deep rotating prefetch; lean <=2-live-D epilogue. This is the
// r15 configuration (41.2 us) — the measured optimum of this structure class
// over SROWS/NSLICE/prefetch/register-class parameter space (r10-r19).
__global__ __launch_bounds__(256, 4)
void chamfer_mfma_kernel(const bf16x8* __restrict__ Ar, const bf16x8* __restrict__ Bd,
                         const bf16x8* __restrict__ Ad, const bf16x8* __restrict__ Br,
                         float* __restrict__ part_data,   // [B][N/256][M]
                         float* __restrict__ part_rec,    // [B][M/256][N]
                         int N, int M, int B)
{
    const int nSB1 = N / SROWS;
    const int G1   = B * nSB1 * NSLICE;

    const bf16x8* Ap; const bf16x8* Bp; float* outp;
    int S, T, idx;
    if ((int)blockIdx.x < G1) {
        Ap = Ar; Bp = Bd; outp = part_data; S = N; T = M; idx = blockIdx.x;
    } else {
        Ap = Ad; Bp = Br; outp = part_rec;  S = M; T = N; idx = blockIdx.x - G1;
    }
    const int nSB = S / SROWS;
    const int sl  = idx % NSLICE; idx /= NSLICE;
    const int sb  = idx % nSB;
    const int b   = idx / nSB;

    const int lane = threadIdx.x & 63, wave = threadIdx.x >> 6;
    const int c = lane & 31, h = lane >> 5;

    const bf16x8* __restrict__ Ab = Ap + 2 * ((size_t)b * S + sb * SROWS);
    const bf16x8* __restrict__ Bb = Bp + 2 * ((size_t)b * T);
    float* __restrict__ outBase = outp + ((size_t)b * nSB + sb) * T;

    bf16x8 a0 = Ab[2 * (0 * 32 + c) + h];
    bf16x8 a1 = Ab[2 * (1 * 32 + c) + h];
    bf16x8 a2 = Ab[2 * (2 * 32 + c) + h];
    bf16x8 a3 = Ab[2 * (3 * 32 + c) + h];
    bf16x8 a4 = Ab[2 * (4 * 32 + c) + h];
    bf16x8 a5 = Ab[2 * (5 * 32 + c) + h];
    bf16x8 a6 = Ab[2 * (6 * 32 + c) + h];
    bf16x8 a7 = Ab[2 * (7 * 32 + c) + h];

    f32x16 zacc;
    #pragma unroll
    for (int r = 0; r < 16; ++r) zacc[r] = 0.f;

    const int TS32   = T >> 5;
    const int TSlice = TS32 / NSLICE;            // 64 col-tiles per slice
    const int t0     = sl * TSlice + wave;
    const int tEnd   = (sl + 1) * TSlice;

    // 2-deep rotating prefetch: loads for t+4 and t+8 in flight while
    // computing t.
    bf16x8 bcur = Bb[2 * ((size_t)t0 * 32 + c) + h];
    bf16x8 bn1  = Bb[2 * ((size_t)(t0 + 4) * 32 + c) + h];

    for (int t = t0; t < tEnd; t += 4) {
        int tn = t + 8; if (tn >= tEnd) tn = t0;            // harmless reload
        bf16x8 bn2 = Bb[2 * ((size_t)tn * 32 + c) + h];     // 2-ahead

        f32x16 d0 = __builtin_amdgcn_mfma_f32_32x32x16_bf16(a0, bcur, zacc, 0, 0, 0);
        f32x16 d1 = __builtin_amdgcn_mfma_f32_32x32x16_bf16(a1, bcur, zacc, 0, 0, 0);
        f32x16 acc;
        #pragma unroll
        for (int r = 0; r < 16; ++r) acc[r] = fminf(d0[r], d1[r]);
        d0 = __builtin_amdgcn_mfma_f32_32x32x16_bf16(a2, bcur, zacc, 0, 0, 0);
        d1 = __builtin_amdgcn_mfma_f32_32x32x16_bf16(a3, bcur, zacc, 0, 0, 0);
        #pragma unroll
        for (int r = 0; r < 16; ++r) acc[r] = fminf(fminf(d0[r], d1[r]), acc[r]);
        d0 = __builtin_amdgcn_mfma_f32_32x32x16_bf16(a4, bcur, zacc, 0, 0, 0);
        d1 = __builtin_amdgcn_mfma_f32_32x32x16_bf16(a5, bcur, zacc, 0, 0, 0);
        #pragma unroll
        for (int r = 0; r < 16; ++r) acc[r] = fminf(fminf(d0[r], d1[r]), acc[r]);
        d0 = __builtin_amdgcn_mfma_f32_32x32x16_bf16(a6, bcur, zacc, 0, 0, 0);
        d1 = __builtin_amdgcn_mfma_f32_32x32x16_bf16(a7, bcur, zacc, 0, 0, 0);
        #pragma unroll
        for (int r = 0; r < 16; ++r) acc[r] = fminf(fminf(d0[r], d1[r]), acc[r]);

        float cm = vmin16_t(acc);                           // lane's 16 rows
        cm = fminf(cm, __shfl_xor(cm, 32));                 // merge halves: 256 rows
        if (lane < 32)
            outBase[(size_t)t * 32 + c] = cm;               // 128B coalesced store

        bcur = bn1; bn1 = bn2;
    }
}

// Stage 2: per point, min over the nSB stationary-block partials, clamp, sum.
__global__ __launch_bounds__(256)
void chamfer_stage2(const float* __restrict__ part_data,
                    const float* __restrict__ part_rec,
                    float* __restrict__ bsums, int N, int M, int B)
{
    __shared__ float wsum[4];
    const int gid = blockIdx.x * 256 + threadIdx.x;
    const int nD = B * M;

    const float* base; size_t stride; int depth;
    if (gid < nD) {
        const int b = gid / M, col = gid - b * M;
        base = part_data + ((size_t)b * (N / SROWS)) * M + col;
        stride = M; depth = N / SROWS;
    } else {
        const int g = gid - nD;
        const int b = g / N, col = g - b * N;
        base = part_rec + ((size_t)b * (M / SROWS)) * N + col;
        stride = N; depth = M / SROWS;
    }
    float m0 = 3.4e38f, m1 = 3.4e38f, m2 = 3.4e38f, m3 = 3.4e38f;
    int s = 0;
    for (; s + 4 <= depth; s += 4) {
        m0 = fminf(m0, base[(s + 0) * stride]);
        m1 = fminf(m1, base[(s + 1) * stride]);
        m2 = fminf(m2, base[(s + 2) * stride]);
        m3 = fminf(m3, base[(s + 3) * stride]);
    }
    for (; s < depth; ++s) m0 = fminf(m0, base[s * stride]);
    float d = fmaxf(fminf(fminf(m0, m1), fminf(m2, m3)), 0.f);

    for (int off = 32; off; off >>= 1) d += __shfl_down(d, off);
    if ((threadIdx.x & 63) == 0) wsum[threadIdx.x >> 6] = d;
    __syncthreads();
    if (threadIdx.x == 0)
        bsums[blockIdx.x] = wsum[0] + wsum[1] + wsum[2] + wsum[3];
}

// Finalize: mean_b( max(recsum_b/N, datasum_b/M) )
__global__ __launch_bounds__(256)
void chamfer_finalize(const float* __restrict__ bsums, float* __restrict__ out,
                      int N, int M, int B)
{
    __shared__ float smem[512];
    __shared__ float seg[16];
    const int ncD = M >> 8, ncR = N >> 8;       // stage2 blocks per batch
    const int nD  = B * ncD, ntot = nD + B * ncR;
    const int tid = threadIdx.x;
    for (int i = tid; i < ntot; i += 256) smem[i] = bsums[i];
    __syncthreads();
    if (tid < 2 * B) {
        const int dir = tid / B, bb = tid % B;   // dir0 = data, dir1 = rec
        float s = 0.f;
        if (dir == 0) for (int i = 0; i < ncD; ++i) s += smem[bb * ncD + i];
        else          for (int i = 0; i < ncR; ++i) s += smem[nD + bb * ncR + i];
        seg[tid] = s;
    }
    __syncthreads();
    if (tid == 0) {
        float acc = 0.f;
        for (int bb = 0; bb < B; ++bb)
            acc += fmaxf(seg[B + bb] / (float)N, seg[bb] / (float)M);
        out[0] = acc / (float)B;
    }
}

extern "C" void kernel_launch(void* const* d_in, const int* in_sizes, int n_in,
                              void* d_out, int out_size, void* d_ws, size_t ws_size,
                              hipStream_t stream)
{
    const float* rec  = (const float*)d_in[0];
    const float* data = (const float*)d_in[1];
    const int B = 4;
    const int N = in_sizes[0] / (B * 3);
    const int M = in_sizes[1] / (B * 3);
    const int tot = B * (N + M);

    // ws: Ar 1MB | Br 1MB | Ad 1MB | Bd 1MB | part_data 4.2MB | part_rec 4.2MB
    char* w = (char*)d_ws;
    bf16x8* Ar = (bf16x8*)w;  w += (size_t)B * N * 2 * sizeof(bf16x8);
    bf16x8* Br = (bf16x8*)w;  w += (size_t)B * N * 2 * sizeof(bf16x8);
    bf16x8* Ad = (bf16x8*)w;  w += (size_t)B * M * 2 * sizeof(bf16x8);
    bf16x8* Bd = (bf16x8*)w;  w += (size_t)B * M * 2 * sizeof(bf16x8);
    float* part_data = (float*)w;  w += (size_t)B * (N / SROWS) * M * sizeof(float);
    float* part_rec  = (float*)w;  w += (size_t)B * (M / SROWS) * N * sizeof(float);
    float* bsums = (float*)w;

    chamfer_prep<<<(tot + 255) / 256, 256, 0, stream>>>(rec, data, Ar, Br, Ad, Bd,
                                                        N, M, B);
    const int G = B * (N / SROWS) * NSLICE + B * (M / SROWS) * NSLICE;  // 1024
    chamfer_mfma_kernel<<<G, 256, 0, stream>>>(Ar, Bd, Ad, Br,
                                               part_data, part_rec, N, M, B);
    chamfer_stage2<<<tot / 256, 256, 0, stream>>>(part_data, part_rec, bsums,
                                                  N, M, B);
    chamfer_finalize<<<1, 256, 0, stream>>>(bsums, (float*)d_out, N, M, B);
}